// Round 1
// baseline (5317.450 us; speedup 1.0000x reference)
//
#include <hip/hip_runtime.h>
#include <hip/hip_bf16.h>

// ELMo: 2-layer biLSTM, B=64 T=256 U=256. Persistent-RNN design:
//  - 8 clusters = (4 rowgroups x 16 rows) x (2 dirs); cluster = 16 WGs.
//  - Each WG holds bf16 slices (16 units = 64 gate cols) of W0,U0,W1,U1 in LDS (128KB).
//  - Per tick tau: layer0 computes step tau, layer1 computes step tau-1 (skewed),
//    one bf16 h-exchange through global + per-tick arrival counter per cluster.
//  - MFMA 16x16x32 bf16, M=16 batch rows. out[0]/out[3] = exact fp32 emb copies.

#define BB 64
#define TT 256
#define TM 255
#define NE 256
#define NU 256
#define NG 1024
#define NSLICE 16
#define ROWG 16
#define NCLUST 8
#define NTICK 256

typedef __attribute__((ext_vector_type(8))) short short8;
typedef __attribute__((ext_vector_type(4))) float f32x4;

__device__ __forceinline__ unsigned short f2bf(float v) {
  unsigned int x = __float_as_uint(v);
  unsigned int r = (x + 0x7FFFu + ((x >> 16) & 1u)) >> 16;
  return (unsigned short)r;
}
__device__ __forceinline__ float sigm(float x) { return 1.f / (1.f + __expf(-x)); }
__device__ __forceinline__ float tanhp(float x) {
  x = fminf(fmaxf(x, -15.f), 15.f);
  float e = __expf(-2.f * x);
  return (1.f - e) / (1.f + e);
}

__global__ void embed_kernel(const int* __restrict__ seqs, const float* __restrict__ E,
                             unsigned short* __restrict__ embb, float* __restrict__ out) {
  int b = blockIdx.x, t = blockIdx.y, d = threadIdx.x;
  int s = seqs[b * TT + t];
  float v = E[(size_t)s * NE + d];
  embb[((size_t)(b * TT + t)) * NE + d] = f2bf(v);
  if (t < TM) out[(((size_t)(0 * BB + b)) * TM + t) * NU + d] = v;       // fxs[0]
  if (t >= 1) out[(((size_t)(3 * BB + b)) * TM + (t - 1)) * NU + d] = v; // bxs[0]
}

__launch_bounds__(256, 1)
__global__ void lstm_kernel(const int* __restrict__ seqs,
                            const float* __restrict__ Wf, const float* __restrict__ Uf,
                            const float* __restrict__ bf,
                            const float* __restrict__ Wb, const float* __restrict__ Ub,
                            const float* __restrict__ bb,
                            const unsigned short* __restrict__ embb,
                            unsigned short* __restrict__ H0, unsigned short* __restrict__ H1,
                            int* __restrict__ ctr, float* __restrict__ out) {
  extern __shared__ char smem[];
  unsigned short* wlds = (unsigned short*)smem;            // 4 mats * 16384 ushort = 128KB
  float* zl = (float*)(smem + 131072);                     // 2*4*16*16 f32 = 8KB
  unsigned char* mskl = (unsigned char*)(smem + 139264);   // 16*256 = 4KB

  int tid = threadIdx.x;
  int blk = blockIdx.x;
  int cluster = blk & 7;   // blk%8 -> same XCD per cluster under round-robin dispatch
  int slice = blk >> 3;    // 0..15
  int dir = cluster >> 2;  // 0=fwd 1=bwd
  int rg = cluster & 3;    // rowgroup
  int ubase = slice << 4;  // unit base

  const float* W0 = dir ? Wb : Wf;
  const float* U0 = dir ? Ub : Uf;
  const float* W1 = W0 + NU * NG;
  const float* U1 = U0 + NU * NG;
  const float* b0p = dir ? bb : bf;
  const float* b1p = b0p + NG;

  // ---- init: mask table msk[row][step] ----
  for (int i = tid; i < ROWG * 256; i += 256) {
    int row = i >> 8, s = i & 255;
    unsigned char m = 0;
    if (s < TM) {
      int traw = dir ? (TM - s) : s;  // bwd step s reads raw time 255-s
      m = (seqs[(rg * ROWG + row) * TT + traw] != 0) ? 1 : 0;
    }
    mskl[i] = m;
  }

  // ---- init: pack weight slices into LDS (bf16, B-fragment layout) ----
  {
    const float* srcs[4] = {W0, U0, W1, U1};
    int c = tid & 63;
    int g = c >> 4, n = c & 15;
    int col = (g << 8) + ubase + n;   // gate*256 + unit
    int koff = tid >> 6;
    for (int m = 0; m < 4; m++) {
      const float* S = srcs[m];
      unsigned short* WL = wlds + m * 16384;
      for (int k0 = 0; k0 < 256; k0 += 4) {
        int k = k0 + koff;
        float v = S[k * NG + col];
        // [g][kb][n][q][j]: k = kb*32 + q*8 + j
        int li = (((g << 3) + (k >> 5)) * 16 + n) * 32 + (((k >> 3) & 3) << 3) + (k & 7);
        WL[li] = f2bf(v);
      }
    }
  }

  // ---- per-thread persistent state: thread (crow, cn) owns unit ubase+cn of row crow
  float bi0[4], bi1[4];
  {
    int cn0 = tid & 15;
    #pragma unroll
    for (int g = 0; g < 4; g++) {
      bi0[g] = b0p[(g << 8) + ubase + cn0];
      bi1[g] = b1p[(g << 8) + ubase + cn0];
    }
  }
  float c0 = 0.f, h0v = 0.f, c1 = 0.f, h1v = 0.f;

  __syncthreads();

  int wave = tid >> 6;          // gate id for MFMA phase
  int lane = tid & 63;
  int q = lane >> 4;
  int n15 = lane & 15;
  int fo = (n15 << 8) + (q << 3);  // A-frag offset inside [16][256] bf16 tile
  int crow = tid >> 4, cn = tid & 15;
  int brow = rg * ROWG + crow;
  int cbase = cluster * (ROWG * NU);  // 4096 ushorts per cluster tile
  int* myctr = ctr + cluster * NTICK;

  for (int tau = 0; tau < NTICK; tau++) {
    bool doL0 = (tau < TM);  // L0 active for tau 0..254; L1 active for tau 1..255

    if (tau > 0) {
      while (__hip_atomic_load(myctr + (tau - 1), __ATOMIC_ACQUIRE,
                               __HIP_MEMORY_SCOPE_AGENT) < NSLICE)
        __builtin_amdgcn_s_sleep(2);
    }

    f32x4 acc0 = {0.f, 0.f, 0.f, 0.f};
    f32x4 acc1 = {0.f, 0.f, 0.f, 0.f};

    int pb = (tau + 1) & 1;  // buffer written at tick tau-1
    const unsigned short* h0p = H0 + pb * (NCLUST * ROWG * NU) + cbase + fo;
    const unsigned short* h1p = H1 + pb * (NCLUST * ROWG * NU) + cbase + fo;

    if (doL0) {  // x-part of layer0: emb @ W0
      int tx = dir ? (TM - tau) : tau;
      const unsigned short* ep =
          embb + ((size_t)((rg * ROWG + n15) * TT + tx)) * NE + (q << 3);
      const unsigned short* wb = wlds + (wave << 12) + (n15 << 5) + (q << 3);
      #pragma unroll
      for (int kb = 0; kb < 8; kb++) {
        short8 a = *reinterpret_cast<const short8*>(ep + (kb << 5));
        short8 b = *reinterpret_cast<const short8*>(wb + (kb << 9));
        acc0 = __builtin_amdgcn_mfma_f32_16x16x32_bf16(a, b, acc0, 0, 0, 0);
      }
    }
    if (tau > 0) {  // h0[tau-1] feeds U0 (layer0) and W1 (layer1 x-part)
      const unsigned short* ub0 = wlds + 16384 + (wave << 12) + (n15 << 5) + (q << 3);
      const unsigned short* wb1 = wlds + 32768 + (wave << 12) + (n15 << 5) + (q << 3);
      #pragma unroll
      for (int kb = 0; kb < 8; kb++) {
        short8 a = *reinterpret_cast<const short8*>(h0p + (kb << 5));
        if (doL0)
          acc0 = __builtin_amdgcn_mfma_f32_16x16x32_bf16(
              a, *reinterpret_cast<const short8*>(ub0 + (kb << 9)), acc0, 0, 0, 0);
        acc1 = __builtin_amdgcn_mfma_f32_16x16x32_bf16(
            a, *reinterpret_cast<const short8*>(wb1 + (kb << 9)), acc1, 0, 0, 0);
      }
      if (tau > 1) {  // h1[tau-2] @ U1
        const unsigned short* ub1 = wlds + 49152 + (wave << 12) + (n15 << 5) + (q << 3);
        #pragma unroll
        for (int kb = 0; kb < 8; kb++) {
          short8 a = *reinterpret_cast<const short8*>(h1p + (kb << 5));
          acc1 = __builtin_amdgcn_mfma_f32_16x16x32_bf16(
              a, *reinterpret_cast<const short8*>(ub1 + (kb << 9)), acc1, 0, 0, 0);
        }
      }
    }

    // stage z tiles to LDS (C layout: col=lane&15, row=(lane>>4)*4+j  [m89-verified])
    if (doL0) {
      #pragma unroll
      for (int j = 0; j < 4; j++)
        zl[(wave << 8) + (((q << 2) + j) << 4) + n15] = acc0[j];
    }
    if (tau > 0) {
      #pragma unroll
      for (int j = 0; j < 4; j++)
        zl[1024 + (wave << 8) + (((q << 2) + j) << 4) + n15] = acc1[j];
    }
    __syncthreads();

    // combine: gate math + mask-carry + outputs + h exchange
    if (doL0) {
      float zi = zl[(crow << 4) + cn] + bi0[0];
      float zf = zl[256 + (crow << 4) + cn] + bi0[1];
      float zg = zl[512 + (crow << 4) + cn] + bi0[2];
      float zo = zl[768 + (crow << 4) + cn] + bi0[3];
      float cnw = sigm(zf) * c0 + sigm(zi) * tanhp(zg);
      float hnw = sigm(zo) * tanhp(cnw);
      if (mskl[(crow << 8) + tau]) { c0 = cnw; h0v = hnw; }
      int tout = dir ? (TM - 1 - tau) : tau;
      out[(((size_t)((1 + dir * 3) * BB + brow)) * TM + tout) * NU + ubase + cn] = h0v;
      H0[((tau & 1) * (NCLUST * ROWG * NU)) + cbase + (crow << 8) + ubase + cn] = f2bf(h0v);
    }
    if (tau > 0) {
      int t1 = tau - 1;
      float zi = zl[1024 + (crow << 4) + cn] + bi1[0];
      float zf = zl[1024 + 256 + (crow << 4) + cn] + bi1[1];
      float zg = zl[1024 + 512 + (crow << 4) + cn] + bi1[2];
      float zo = zl[1024 + 768 + (crow << 4) + cn] + bi1[3];
      float cnw = sigm(zf) * c1 + sigm(zi) * tanhp(zg);
      float hnw = sigm(zo) * tanhp(cnw);
      if (mskl[(crow << 8) + t1]) { c1 = cnw; h1v = hnw; }
      int tout = dir ? (TM - 1 - t1) : t1;
      out[(((size_t)((2 + dir * 3) * BB + brow)) * TM + tout) * NU + ubase + cn] = h1v;
      H1[((tau & 1) * (NCLUST * ROWG * NU)) + cbase + (crow << 8) + ubase + cn] = f2bf(h1v);
    }

    if (tau < TM) {  // publish this tick
      __threadfence();
      __syncthreads();
      if (tid == 0)
        __hip_atomic_fetch_add(myctr + tau, 1, __ATOMIC_RELEASE, __HIP_MEMORY_SCOPE_AGENT);
    }
  }
}

extern "C" void kernel_launch(void* const* d_in, const int* in_sizes, int n_in,
                              void* d_out, int out_size, void* d_ws, size_t ws_size,
                              hipStream_t stream) {
  const int* seqs = (const int*)d_in[0];
  const float* E = (const float*)d_in[1];
  const float* Wf = (const float*)d_in[2];
  const float* Uf = (const float*)d_in[3];
  const float* bfp = (const float*)d_in[4];
  const float* Wb = (const float*)d_in[5];
  const float* Ub = (const float*)d_in[6];
  const float* bbp = (const float*)d_in[7];
  float* out = (float*)d_out;

  char* ws = (char*)d_ws;
  int* ctr = (int*)ws;                                        // 8 KB
  unsigned short* embb = (unsigned short*)(ws + 65536);       // 8 MB bf16 emb
  unsigned short* H0 = (unsigned short*)(ws + 65536 + 8388608);  // 128 KB
  unsigned short* H1 = H0 + 2 * NCLUST * ROWG * NU;              // 128 KB

  hipMemsetAsync(ctr, 0, NCLUST * NTICK * sizeof(int), stream);

  hipLaunchKernelGGL(embed_kernel, dim3(BB, TT), dim3(256), 0, stream,
                     seqs, E, embb, out);

  int smem = 143360;  // 128KB weights + 8KB z + 4KB mask + pad
  hipFuncSetAttribute(reinterpret_cast<const void*>(lstm_kernel),
                      hipFuncAttributeMaxDynamicSharedMemorySize, smem);
  hipLaunchKernelGGL(lstm_kernel, dim3(128), dim3(256), smem, stream,
                     seqs, Wf, Uf, bfp, Wb, Ub, bbp, embb, H0, H1, ctr, out);
}

// Round 2
// 2455.758 us; speedup vs baseline: 2.1653x; 2.1653x over previous
//
#include <hip/hip_runtime.h>
#include <hip/hip_bf16.h>

// ELMo: 2-layer biLSTM, B=64 T=256 U=256. Persistent-RNN, fence-free sync:
//  - 8 clusters = (4 rowgroups x 16 rows) x (2 dirs); cluster = 16 WGs.
//  - Each WG holds bf16 slices (16 units = 64 gate cols) of W0,U0,W1,U1 in LDS (128KB).
//  - Per tick tau: L0 computes step tau, L1 computes step tau-1 (skewed).
//  - h exchange: relaxed agent-scope atomic u32 (sc1 write-through, no L2 fences);
//    publish = vmcnt-drained barrier + relaxed counter add; tid0-only spin.

#define BB 64
#define TT 256
#define TM 255
#define NE 256
#define NU 256
#define NG 1024
#define NSLICE 16
#define ROWG 16
#define NCLUST 8
#define NTICK 256
#define HSTRIDE (NCLUST * ROWG * NU)

typedef __attribute__((ext_vector_type(8))) short short8;
typedef __attribute__((ext_vector_type(4))) float f32x4;

__device__ __forceinline__ unsigned short f2bf(float v) {
  unsigned int x = __float_as_uint(v);
  unsigned int r = (x + 0x7FFFu + ((x >> 16) & 1u)) >> 16;
  return (unsigned short)r;
}
__device__ __forceinline__ float sigm(float x) { return 1.f / (1.f + __expf(-x)); }
__device__ __forceinline__ float tanhp(float x) {
  x = fminf(fmaxf(x, -15.f), 15.f);
  float e = __expf(-2.f * x);
  return (1.f - e) / (1.f + e);
}

// coherent-point (agent) relaxed dword load of a bf16 h-fragment (16B)
__device__ __forceinline__ short8 load_hfrag(const unsigned short* p) {
  const unsigned int* q = (const unsigned int*)p;
  union { unsigned int u[4]; short8 s; } r;
  #pragma unroll
  for (int i = 0; i < 4; i++)
    r.u[i] = __hip_atomic_load(q + i, __ATOMIC_RELAXED, __HIP_MEMORY_SCOPE_AGENT);
  return r.s;
}

__global__ void embed_kernel(const int* __restrict__ seqs, const float* __restrict__ E,
                             unsigned short* __restrict__ embb, float* __restrict__ out) {
  int b = blockIdx.x, t = blockIdx.y, d = threadIdx.x;
  int s = seqs[b * TT + t];
  float v = E[(size_t)s * NE + d];
  embb[((size_t)(b * TT + t)) * NE + d] = f2bf(v);
  if (t < TM) out[(((size_t)(0 * BB + b)) * TM + t) * NU + d] = v;       // fxs[0]
  if (t >= 1) out[(((size_t)(3 * BB + b)) * TM + (t - 1)) * NU + d] = v; // bxs[0]
}

__launch_bounds__(256, 1)
__global__ void lstm_kernel(const int* __restrict__ seqs,
                            const float* __restrict__ Wf, const float* __restrict__ Uf,
                            const float* __restrict__ bf,
                            const float* __restrict__ Wb, const float* __restrict__ Ub,
                            const float* __restrict__ bb,
                            const unsigned short* __restrict__ embb,
                            unsigned short* __restrict__ H0, unsigned short* __restrict__ H1,
                            int* __restrict__ ctr, float* __restrict__ out) {
  extern __shared__ char smem[];
  unsigned short* wlds = (unsigned short*)smem;            // 4 mats * 16384 ushort = 128KB
  float* zl = (float*)(smem + 131072);                     // 8*16*17 f32 = 8704B (padded)
  unsigned char* mskl = (unsigned char*)(smem + 131072 + 8704);  // 16*256 = 4KB

  int tid = threadIdx.x;
  int blk = blockIdx.x;
  int cluster = blk & 7;   // blk%8 -> same XCD per cluster under round-robin dispatch
  int slice = blk >> 3;    // 0..15
  int dir = cluster >> 2;  // 0=fwd 1=bwd
  int rg = cluster & 3;    // rowgroup
  int ubase = slice << 4;  // unit base

  const float* W0 = dir ? Wb : Wf;
  const float* U0 = dir ? Ub : Uf;
  const float* W1 = W0 + NU * NG;
  const float* U1 = U0 + NU * NG;
  const float* b0p = dir ? bb : bf;
  const float* b1p = b0p + NG;

  // ---- init: mask table msk[row][step] ----
  for (int i = tid; i < ROWG * 256; i += 256) {
    int row = i >> 8, s = i & 255;
    unsigned char m = 0;
    if (s < TM) {
      int traw = dir ? (TM - s) : s;  // bwd step s reads raw time 255-s
      m = (seqs[(rg * ROWG + row) * TT + traw] != 0) ? 1 : 0;
    }
    mskl[i] = m;
  }

  // ---- init: pack weight slices into LDS (bf16, contiguous-per-lane B-frag layout)
  // element (gate g, col n, k) -> li = (g<<12)+(kb<<9)+(q<<7)+(n<<3)+j,
  // kb=k>>5, q=(k>>3)&3, j=k&7. Lane (q,n) then reads contiguous 16B: conflict-free.
  {
    const float* srcs[4] = {W0, U0, W1, U1};
    int c = tid & 63;
    int g = c >> 4, n = c & 15;
    int col = (g << 8) + ubase + n;   // gate*256 + unit
    int koff = tid >> 6;
    for (int m = 0; m < 4; m++) {
      const float* S = srcs[m];
      unsigned short* WL = wlds + m * 16384;
      for (int k0 = 0; k0 < 256; k0 += 4) {
        int k = k0 + koff;
        float v = S[k * NG + col];
        int li = (g << 12) + ((k >> 5) << 9) + (((k >> 3) & 3) << 7) + (n << 3) + (k & 7);
        WL[li] = f2bf(v);
      }
    }
  }

  // ---- per-thread persistent state: thread (crow, cn) owns unit ubase+cn of row crow
  float bi0[4], bi1[4];
  {
    int cn0 = tid & 15;
    #pragma unroll
    for (int g = 0; g < 4; g++) {
      bi0[g] = b0p[(g << 8) + ubase + cn0];
      bi1[g] = b1p[(g << 8) + ubase + cn0];
    }
  }
  float c0 = 0.f, h0v = 0.f, c1 = 0.f, h1v = 0.f;

  __syncthreads();

  int wave = tid >> 6;          // gate id for MFMA phase
  int lane = tid & 63;
  int q = lane >> 4;
  int n15 = lane & 15;
  int fo = (n15 << 8) + (q << 3);  // A-frag offset inside [16][256] bf16 tile
  int crow = tid >> 4, cn = tid & 15;
  int brow = rg * ROWG + crow;
  int cbase = cluster * (ROWG * NU);  // 4096 ushorts per cluster tile
  int* myctr = ctr + cluster * NTICK;

  const unsigned short* wb0 = wlds + (wave << 12) + (q << 7) + (n15 << 3);
  const unsigned short* ub0 = wb0 + 16384;
  const unsigned short* wb1 = wb0 + 32768;
  const unsigned short* ub1 = wb0 + 49152;

  for (int tau = 0; tau < NTICK; tau++) {
    bool doL0 = (tau < TM);  // L0 active for tau 0..254; L1 active for tau 1..255

    f32x4 acc0 = {0.f, 0.f, 0.f, 0.f};
    f32x4 acc1 = {0.f, 0.f, 0.f, 0.f};

    // ---- Phase A (pre-spin, no cross-WG dep): x-part of layer0 = emb @ W0
    if (doL0) {
      int tx = dir ? (TM - tau) : tau;
      const unsigned short* ep =
          embb + ((size_t)((rg * ROWG + n15) * TT + tx)) * NE + (q << 3);
      #pragma unroll
      for (int kb = 0; kb < 8; kb++) {
        short8 a = *reinterpret_cast<const short8*>(ep + (kb << 5));
        short8 b = *reinterpret_cast<const short8*>(wb0 + (kb << 9));
        acc0 = __builtin_amdgcn_mfma_f32_16x16x32_bf16(a, b, acc0, 0, 0, 0);
      }
    }

    // ---- spin (tid0 only, relaxed) for tick tau-1 publication, then barrier
    if (tau > 0) {
      if (tid == 0) {
        while (__hip_atomic_load(myctr + (tau - 1), __ATOMIC_RELAXED,
                                 __HIP_MEMORY_SCOPE_AGENT) < NSLICE) {}
      }
      __syncthreads();

      int pb = (tau + 1) & 1;  // buffer written at tick tau-1
      // h0[tau-1] feeds U0 (layer0) and W1 (layer1 x-part)
      const unsigned short* h0p = H0 + pb * HSTRIDE + cbase + fo;
      short8 ha[8];
      #pragma unroll
      for (int kb = 0; kb < 8; kb++) ha[kb] = load_hfrag(h0p + (kb << 5));
      #pragma unroll
      for (int kb = 0; kb < 8; kb++) {
        if (doL0)
          acc0 = __builtin_amdgcn_mfma_f32_16x16x32_bf16(
              ha[kb], *reinterpret_cast<const short8*>(ub0 + (kb << 9)), acc0, 0, 0, 0);
        acc1 = __builtin_amdgcn_mfma_f32_16x16x32_bf16(
            ha[kb], *reinterpret_cast<const short8*>(wb1 + (kb << 9)), acc1, 0, 0, 0);
      }
      if (tau > 1) {  // h1[tau-2] @ U1
        const unsigned short* h1p = H1 + pb * HSTRIDE + cbase + fo;
        short8 hb[8];
        #pragma unroll
        for (int kb = 0; kb < 8; kb++) hb[kb] = load_hfrag(h1p + (kb << 5));
        #pragma unroll
        for (int kb = 0; kb < 8; kb++)
          acc1 = __builtin_amdgcn_mfma_f32_16x16x32_bf16(
              hb[kb], *reinterpret_cast<const short8*>(ub1 + (kb << 9)), acc1, 0, 0, 0);
      }
    }

    // ---- stage z tiles to LDS (C layout: col=lane&15, row=(lane>>4)*4+j; stride 17)
    if (doL0) {
      #pragma unroll
      for (int j = 0; j < 4; j++)
        zl[(wave * 16 + (q << 2) + j) * 17 + n15] = acc0[j];
    }
    if (tau > 0) {
      #pragma unroll
      for (int j = 0; j < 4; j++)
        zl[((4 + wave) * 16 + (q << 2) + j) * 17 + n15] = acc1[j];
    }
    __syncthreads();

    // ---- combine: gate math + mask-carry; publish H first, out[] later
    if (doL0) {
      float zi = zl[(0 * 16 + crow) * 17 + cn] + bi0[0];
      float zf = zl[(1 * 16 + crow) * 17 + cn] + bi0[1];
      float zg = zl[(2 * 16 + crow) * 17 + cn] + bi0[2];
      float zo = zl[(3 * 16 + crow) * 17 + cn] + bi0[3];
      float cnw = sigm(zf) * c0 + sigm(zi) * tanhp(zg);
      float hnw = sigm(zo) * tanhp(cnw);
      if (mskl[(crow << 8) + tau]) { c0 = cnw; h0v = hnw; }
      unsigned int hb16 = f2bf(h0v);
      unsigned int othr = (unsigned int)__shfl_xor((int)hb16, 1, 64);
      if (!(cn & 1)) {
        unsigned int packed = (hb16 & 0xFFFFu) | (othr << 16);
        __hip_atomic_store(
            (unsigned int*)(H0 + (tau & 1) * HSTRIDE + cbase + (crow << 8) + ubase + cn),
            packed, __ATOMIC_RELAXED, __HIP_MEMORY_SCOPE_AGENT);
      }
    }
    if (tau > 0) {
      int t1 = tau - 1;
      float zi = zl[((4 + 0) * 16 + crow) * 17 + cn] + bi1[0];
      float zf = zl[((4 + 1) * 16 + crow) * 17 + cn] + bi1[1];
      float zg = zl[((4 + 2) * 16 + crow) * 17 + cn] + bi1[2];
      float zo = zl[((4 + 3) * 16 + crow) * 17 + cn] + bi1[3];
      float cnw = sigm(zf) * c1 + sigm(zi) * tanhp(zg);
      float hnw = sigm(zo) * tanhp(cnw);
      if (mskl[(crow << 8) + t1]) { c1 = cnw; h1v = hnw; }
      unsigned int hb16 = f2bf(h1v);
      unsigned int othr = (unsigned int)__shfl_xor((int)hb16, 1, 64);
      if (!(cn & 1)) {
        unsigned int packed = (hb16 & 0xFFFFu) | (othr << 16);
        __hip_atomic_store(
            (unsigned int*)(H1 + (tau & 1) * HSTRIDE + cbase + (crow << 8) + ubase + cn),
            packed, __ATOMIC_RELAXED, __HIP_MEMORY_SCOPE_AGENT);
      }
    }

    // ---- publish: barrier drains each wave's vmcnt (stores ack'd at coherent
    // point for sc1 write-through), then one relaxed counter bump.
    __syncthreads();
    if (tau < TM && tid == 0)
      __hip_atomic_fetch_add(myctr + tau, 1, __ATOMIC_RELAXED, __HIP_MEMORY_SCOPE_AGENT);

    // ---- out[] fp32 stores (off critical path)
    if (doL0) {
      int tout = dir ? (TM - 1 - tau) : tau;
      out[(((size_t)((1 + dir * 3) * BB + brow)) * TM + tout) * NU + ubase + cn] = h0v;
    }
    if (tau > 0) {
      int t1 = tau - 1;
      int tout = dir ? (TM - 1 - t1) : t1;
      out[(((size_t)((2 + dir * 3) * BB + brow)) * TM + tout) * NU + ubase + cn] = h1v;
    }
  }
}

extern "C" void kernel_launch(void* const* d_in, const int* in_sizes, int n_in,
                              void* d_out, int out_size, void* d_ws, size_t ws_size,
                              hipStream_t stream) {
  const int* seqs = (const int*)d_in[0];
  const float* E = (const float*)d_in[1];
  const float* Wf = (const float*)d_in[2];
  const float* Uf = (const float*)d_in[3];
  const float* bfp = (const float*)d_in[4];
  const float* Wb = (const float*)d_in[5];
  const float* Ub = (const float*)d_in[6];
  const float* bbp = (const float*)d_in[7];
  float* out = (float*)d_out;

  char* ws = (char*)d_ws;
  int* ctr = (int*)ws;                                        // 8 KB
  unsigned short* embb = (unsigned short*)(ws + 65536);       // 8 MB bf16 emb
  unsigned short* H0 = (unsigned short*)(ws + 65536 + 8388608);  // 2x64KB
  unsigned short* H1 = H0 + 2 * HSTRIDE;

  hipMemsetAsync(ctr, 0, NCLUST * NTICK * sizeof(int), stream);

  hipLaunchKernelGGL(embed_kernel, dim3(BB, TT), dim3(256), 0, stream,
                     seqs, E, embb, out);

  int smem = 131072 + 8704 + 4096;  // weights + padded z + mask = 143872
  hipFuncSetAttribute(reinterpret_cast<const void*>(lstm_kernel),
                      hipFuncAttributeMaxDynamicSharedMemorySize, smem);
  hipLaunchKernelGGL(lstm_kernel, dim3(128), dim3(256), smem, stream,
                     seqs, Wf, Uf, bfp, Wb, Ub, bbp, embb, H0, H1, ctr, out);
}

// Round 3
// 938.734 us; speedup vs baseline: 5.6645x; 2.6160x over previous
//
#include <hip/hip_runtime.h>
#include <hip/hip_bf16.h>

// ELMo: 2-layer biLSTM, B=64 T=256 U=256. Persistent-RNN, fence-free sync:
//  - 8 clusters = (4 rowgroups x 16 rows) x (2 dirs); cluster = 16 WGs.
//  - Each WG holds bf16 slices (16 units = 64 gate cols) of W0,U0,W1,U1 in LDS (128KB).
//  - Per tick tau: L0 computes step tau, L1 computes step tau-1 (skewed).
//  - h exchange: producers store packed u32 (relaxed agent atomics, sc1
//    write-through); consumers do COOPERATIVE 16B sc0sc1 loads -> swizzled LDS
//    tile -> ds_read_b128 frags. tid0-only relaxed spin on per-tick counter.

#define BB 64
#define TT 256
#define TM 255
#define NE 256
#define NU 256
#define NG 1024
#define NSLICE 16
#define ROWG 16
#define NCLUST 8
#define NTICK 256
#define HSTRIDE (NCLUST * ROWG * NU)

typedef __attribute__((ext_vector_type(8))) short short8;
typedef __attribute__((ext_vector_type(4))) float f32x4;
typedef __attribute__((ext_vector_type(4))) unsigned int u32x4;

__device__ __forceinline__ unsigned short f2bf(float v) {
  unsigned int x = __float_as_uint(v);
  unsigned int r = (x + 0x7FFFu + ((x >> 16) & 1u)) >> 16;
  return (unsigned short)r;
}
__device__ __forceinline__ float sigm(float x) { return 1.f / (1.f + __expf(-x)); }
__device__ __forceinline__ float tanhp(float x) {
  x = fminf(fmaxf(x, -15.f), 15.f);
  float e = __expf(-2.f * x);
  return (1.f - e) / (1.f + e);
}

// 16B load that bypasses L1/L2 (coherent at LLC) — matches producers' sc1 stores.
__device__ __forceinline__ u32x4 llc_load16(const unsigned short* p) {
  u32x4 r;
  asm volatile("global_load_dwordx4 %0, %1, off sc0 sc1" : "=v"(r) : "v"(p));
  return r;
}

__global__ void embed_kernel(const int* __restrict__ seqs, const float* __restrict__ E,
                             unsigned short* __restrict__ embb, float* __restrict__ out) {
  int b = blockIdx.x, t = blockIdx.y, d = threadIdx.x;
  int s = seqs[b * TT + t];
  float v = E[(size_t)s * NE + d];
  embb[((size_t)(b * TT + t)) * NE + d] = f2bf(v);
  if (t < TM) out[(((size_t)(0 * BB + b)) * TM + t) * NU + d] = v;       // fxs[0]
  if (t >= 1) out[(((size_t)(3 * BB + b)) * TM + (t - 1)) * NU + d] = v; // bxs[0]
}

__launch_bounds__(256, 1)
__global__ void lstm_kernel(const int* __restrict__ seqs,
                            const float* __restrict__ Wf, const float* __restrict__ Uf,
                            const float* __restrict__ bf,
                            const float* __restrict__ Wb, const float* __restrict__ Ub,
                            const float* __restrict__ bb,
                            const unsigned short* __restrict__ embb,
                            unsigned short* __restrict__ H0, unsigned short* __restrict__ H1,
                            int* __restrict__ ctr, float* __restrict__ out) {
  extern __shared__ char smem[];
  unsigned short* wlds = (unsigned short*)smem;               // 4 mats * 16384 ushort = 128KB
  float* zl = (float*)(smem + 131072);                        // 8*16*17 f32 = 8704B
  unsigned char* mskl = (unsigned char*)(smem + 139776);      // 16*256 = 4KB
  char* hlb0 = smem + 143872;                                 // 8KB swizzled h0 tile
  char* hlb1 = smem + 152064;                                 // 8KB swizzled h1 tile

  int tid = threadIdx.x;
  int blk = blockIdx.x;
  int cluster = blk & 7;   // L2-locality heuristic only (correctness is agent-scope)
  int slice = blk >> 3;    // 0..15
  int dir = cluster >> 2;  // 0=fwd 1=bwd
  int rg = cluster & 3;    // rowgroup
  int ubase = slice << 4;  // unit base

  const float* W0 = dir ? Wb : Wf;
  const float* U0 = dir ? Ub : Uf;
  const float* W1 = W0 + NU * NG;
  const float* U1 = U0 + NU * NG;
  const float* b0p = dir ? bb : bf;
  const float* b1p = b0p + NG;

  // ---- init: mask table msk[row][step] ----
  for (int i = tid; i < ROWG * 256; i += 256) {
    int row = i >> 8, s = i & 255;
    unsigned char m = 0;
    if (s < TM) {
      int traw = dir ? (TM - s) : s;
      m = (seqs[(rg * ROWG + row) * TT + traw] != 0) ? 1 : 0;
    }
    mskl[i] = m;
  }

  // ---- init: pack weight slices into LDS (bf16, contiguous-per-lane B-frag layout)
  {
    const float* srcs[4] = {W0, U0, W1, U1};
    int c = tid & 63;
    int g = c >> 4, n = c & 15;
    int col = (g << 8) + ubase + n;   // gate*256 + unit
    int koff = tid >> 6;
    for (int m = 0; m < 4; m++) {
      const float* S = srcs[m];
      unsigned short* WL = wlds + m * 16384;
      for (int k0 = 0; k0 < 256; k0 += 4) {
        int k = k0 + koff;
        float v = S[k * NG + col];
        int li = (g << 12) + ((k >> 5) << 9) + (((k >> 3) & 3) << 7) + (n << 3) + (k & 7);
        WL[li] = f2bf(v);
      }
    }
  }

  float bi0[4], bi1[4];
  {
    int cn0 = tid & 15;
    #pragma unroll
    for (int g = 0; g < 4; g++) {
      bi0[g] = b0p[(g << 8) + ubase + cn0];
      bi1[g] = b1p[(g << 8) + ubase + cn0];
    }
  }
  float c0 = 0.f, h0v = 0.f, c1 = 0.f, h1v = 0.f;

  __syncthreads();

  int wave = tid >> 6;          // gate id for MFMA phase
  int lane = tid & 63;
  int q = lane >> 4;
  int n15 = lane & 15;
  int crow = tid >> 4, cn = tid & 15;
  int brow = rg * ROWG + crow;
  int cbase = cluster * (ROWG * NU);  // 4096 ushorts per cluster tile
  int* myctr = ctr + cluster * NTICK;

  const unsigned short* wb0 = wlds + (wave << 12) + (q << 7) + (n15 << 3);
  const unsigned short* ub0 = wb0 + 16384;
  const unsigned short* wb1 = wb0 + 32768;
  const unsigned short* ub1 = wb0 + 49152;

  // swizzled frag byte offsets (XOR (row&7)<<4; same involution on write & read)
  int fswz = (n15 & 7) << 4;
  int fbase = (n15 << 9) + (q << 4);  // n15*512 + q*16

  for (int tau = 0; tau < NTICK; tau++) {
    bool doL0 = (tau < TM);

    f32x4 acc0 = {0.f, 0.f, 0.f, 0.f};
    f32x4 acc1 = {0.f, 0.f, 0.f, 0.f};

    // ---- Phase A (pre-spin, no cross-WG dep): x-part of layer0 = emb @ W0
    if (doL0) {
      int tx = dir ? (TM - tau) : tau;
      const unsigned short* ep =
          embb + ((size_t)((rg * ROWG + n15) * TT + tx)) * NE + (q << 3);
      #pragma unroll
      for (int kb = 0; kb < 8; kb++) {
        short8 a = *reinterpret_cast<const short8*>(ep + (kb << 5));
        short8 b = *reinterpret_cast<const short8*>(wb0 + (kb << 9));
        acc0 = __builtin_amdgcn_mfma_f32_16x16x32_bf16(a, b, acc0, 0, 0, 0);
      }
    }

    if (tau > 0) {
      // ---- spin (tid0 only, relaxed) for tick tau-1, then barrier
      if (tid == 0) {
        while (__hip_atomic_load(myctr + (tau - 1), __ATOMIC_RELAXED,
                                 __HIP_MEMORY_SCOPE_AGENT) < NSLICE) {}
      }
      __syncthreads();

      // ---- cooperative 16B LLC loads of h tiles -> swizzled LDS
      int pb = (tau + 1) & 1;
      const unsigned short* src0 = H0 + pb * HSTRIDE + cbase;
      const unsigned short* src1 = H1 + pb * HSTRIDE + cbase;
      int c0i = tid, c1i = tid + 256;
      u32x4 t0a = llc_load16(src0 + c0i * 8);
      u32x4 t0b = llc_load16(src0 + c1i * 8);
      u32x4 t1a, t1b;
      bool doH1 = (tau > 1);
      if (doH1) {
        t1a = llc_load16(src1 + c0i * 8);
        t1b = llc_load16(src1 + c1i * 8);
      }
      asm volatile("s_waitcnt vmcnt(0)" ::: "memory");
      __builtin_amdgcn_sched_barrier(0);
      int w0 = (c0i * 16) ^ ((((unsigned)c0i >> 5) & 7) << 4);
      int w1 = (c1i * 16) ^ ((((unsigned)c1i >> 5) & 7) << 4);
      *(u32x4*)(hlb0 + w0) = t0a;
      *(u32x4*)(hlb0 + w1) = t0b;
      if (doH1) {
        *(u32x4*)(hlb1 + w0) = t1a;
        *(u32x4*)(hlb1 + w1) = t1b;
      }
      __syncthreads();

      // ---- h0[tau-1] @ U0 (L0) and @ W1 (L1 x-part), frags from LDS
      short8 ha[8];
      #pragma unroll
      for (int kb = 0; kb < 8; kb++)
        ha[kb] = *(const short8*)(hlb0 + (((fbase + (kb << 6))) ^ fswz));
      #pragma unroll
      for (int kb = 0; kb < 8; kb++) {
        if (doL0)
          acc0 = __builtin_amdgcn_mfma_f32_16x16x32_bf16(
              ha[kb], *reinterpret_cast<const short8*>(ub0 + (kb << 9)), acc0, 0, 0, 0);
        acc1 = __builtin_amdgcn_mfma_f32_16x16x32_bf16(
            ha[kb], *reinterpret_cast<const short8*>(wb1 + (kb << 9)), acc1, 0, 0, 0);
      }
      if (doH1) {  // h1[tau-2] @ U1
        short8 hb[8];
        #pragma unroll
        for (int kb = 0; kb < 8; kb++)
          hb[kb] = *(const short8*)(hlb1 + (((fbase + (kb << 6))) ^ fswz));
        #pragma unroll
        for (int kb = 0; kb < 8; kb++)
          acc1 = __builtin_amdgcn_mfma_f32_16x16x32_bf16(
              hb[kb], *reinterpret_cast<const short8*>(ub1 + (kb << 9)), acc1, 0, 0, 0);
      }
    }

    // ---- stage z tiles to LDS (C layout: col=lane&15, row=(lane>>4)*4+j; stride 17)
    if (doL0) {
      #pragma unroll
      for (int j = 0; j < 4; j++)
        zl[(wave * 16 + (q << 2) + j) * 17 + n15] = acc0[j];
    }
    if (tau > 0) {
      #pragma unroll
      for (int j = 0; j < 4; j++)
        zl[((4 + wave) * 16 + (q << 2) + j) * 17 + n15] = acc1[j];
    }
    __syncthreads();

    // ---- combine: gate math + mask-carry; H stores (relaxed agent, packed u32)
    if (doL0) {
      float zi = zl[(0 * 16 + crow) * 17 + cn] + bi0[0];
      float zf = zl[(1 * 16 + crow) * 17 + cn] + bi0[1];
      float zg = zl[(2 * 16 + crow) * 17 + cn] + bi0[2];
      float zo = zl[(3 * 16 + crow) * 17 + cn] + bi0[3];
      float cnw = sigm(zf) * c0 + sigm(zi) * tanhp(zg);
      float hnw = sigm(zo) * tanhp(cnw);
      if (mskl[(crow << 8) + tau]) { c0 = cnw; h0v = hnw; }
      unsigned int hb16 = f2bf(h0v);
      unsigned int othr = (unsigned int)__shfl_xor((int)hb16, 1, 64);
      if (!(cn & 1)) {
        unsigned int packed = (hb16 & 0xFFFFu) | (othr << 16);
        __hip_atomic_store(
            (unsigned int*)(H0 + (tau & 1) * HSTRIDE + cbase + (crow << 8) + ubase + cn),
            packed, __ATOMIC_RELAXED, __HIP_MEMORY_SCOPE_AGENT);
      }
    }
    if (tau > 0) {
      int t1 = tau - 1;
      float zi = zl[((4 + 0) * 16 + crow) * 17 + cn] + bi1[0];
      float zf = zl[((4 + 1) * 16 + crow) * 17 + cn] + bi1[1];
      float zg = zl[((4 + 2) * 16 + crow) * 17 + cn] + bi1[2];
      float zo = zl[((4 + 3) * 16 + crow) * 17 + cn] + bi1[3];
      float cnw = sigm(zf) * c1 + sigm(zi) * tanhp(zg);
      float hnw = sigm(zo) * tanhp(cnw);
      if (mskl[(crow << 8) + t1]) { c1 = cnw; h1v = hnw; }
      unsigned int hb16 = f2bf(h1v);
      unsigned int othr = (unsigned int)__shfl_xor((int)hb16, 1, 64);
      if (!(cn & 1)) {
        unsigned int packed = (hb16 & 0xFFFFu) | (othr << 16);
        __hip_atomic_store(
            (unsigned int*)(H1 + (tau & 1) * HSTRIDE + cbase + (crow << 8) + ubase + cn),
            packed, __ATOMIC_RELAXED, __HIP_MEMORY_SCOPE_AGENT);
      }
    }

    // ---- publish: barrier drains vmcnt (sc1 stores ack'd), then counter bump
    __syncthreads();
    if (tau < TM && tid == 0)
      __hip_atomic_fetch_add(myctr + tau, 1, __ATOMIC_RELAXED, __HIP_MEMORY_SCOPE_AGENT);

    // ---- out[] fp32 stores (off critical path; drained by next tick's barrier)
    if (doL0) {
      int tout = dir ? (TM - 1 - tau) : tau;
      out[(((size_t)((1 + dir * 3) * BB + brow)) * TM + tout) * NU + ubase + cn] = h0v;
    }
    if (tau > 0) {
      int t1 = tau - 1;
      int tout = dir ? (TM - 1 - t1) : t1;
      out[(((size_t)((2 + dir * 3) * BB + brow)) * TM + tout) * NU + ubase + cn] = h1v;
    }
  }
}

extern "C" void kernel_launch(void* const* d_in, const int* in_sizes, int n_in,
                              void* d_out, int out_size, void* d_ws, size_t ws_size,
                              hipStream_t stream) {
  const int* seqs = (const int*)d_in[0];
  const float* E = (const float*)d_in[1];
  const float* Wf = (const float*)d_in[2];
  const float* Uf = (const float*)d_in[3];
  const float* bfp = (const float*)d_in[4];
  const float* Wb = (const float*)d_in[5];
  const float* Ub = (const float*)d_in[6];
  const float* bbp = (const float*)d_in[7];
  float* out = (float*)d_out;

  char* ws = (char*)d_ws;
  int* ctr = (int*)ws;                                           // 8 KB
  unsigned short* embb = (unsigned short*)(ws + 65536);          // 8 MB bf16 emb
  unsigned short* H0 = (unsigned short*)(ws + 65536 + 8388608);  // 2x64KB
  unsigned short* H1 = H0 + 2 * HSTRIDE;

  hipMemsetAsync(ctr, 0, NCLUST * NTICK * sizeof(int), stream);

  hipLaunchKernelGGL(embed_kernel, dim3(BB, TT), dim3(256), 0, stream,
                     seqs, E, embb, out);

  int smem = 160256;  // 128K weights + 8704 z + 4K mask + 2x8K h tiles
  hipFuncSetAttribute(reinterpret_cast<const void*>(lstm_kernel),
                      hipFuncAttributeMaxDynamicSharedMemorySize, smem);
  hipLaunchKernelGGL(lstm_kernel, dim3(128), dim3(256), smem, stream,
                     seqs, Wf, Uf, bfp, Wb, Ub, bbp, embb, H0, H1, ctr, out);
}

// Round 4
// 879.993 us; speedup vs baseline: 6.0426x; 1.0668x over previous
//
#include <hip/hip_runtime.h>
#include <hip/hip_bf16.h>

// ELMo: 2-layer biLSTM, B=64 T=256 U=256. Persistent-RNN, fence-free sync:
//  - 8 clusters = (4 rowgroups x 16 rows) x (2 dirs); cluster = 16 WGs.
//  - Each WG: 512 thr (8 waves, 2/SIMD); bf16 slices of W0,U0,W1,U1 in LDS (128KB).
//    Wave (g,kh): gate g, K-half kh. z = sum of kh partials via LDS.
//  - Per tick tau: L0 computes step tau, L1 computes step tau-1 (skewed).
//    Combine split: threads 0-255 do L0, 256-511 do L1 (parallel).
//  - h exchange: relaxed agent u32 stores (sc1 write-through); coop 16B sc0sc1
//    loads -> swizzled LDS -> ds_read_b128 frags. Sync: per-slice FLAG words
//    (no RMW serialization); wave0 polls 16 flags with __all.

#define BB 64
#define TT 256
#define TM 255
#define NE 256
#define NU 256
#define NG 1024
#define NSLICE 16
#define ROWG 16
#define NCLUST 8
#define NTICK 256
#define HSTRIDE (NCLUST * ROWG * NU)

typedef __attribute__((ext_vector_type(8))) short short8;
typedef __attribute__((ext_vector_type(4))) float f32x4;
typedef __attribute__((ext_vector_type(4))) unsigned int u32x4;

__device__ __forceinline__ unsigned short f2bf(float v) {
  unsigned int x = __float_as_uint(v);
  unsigned int r = (x + 0x7FFFu + ((x >> 16) & 1u)) >> 16;
  return (unsigned short)r;
}
__device__ __forceinline__ float sigm(float x) { return 1.f / (1.f + __expf(-x)); }
__device__ __forceinline__ float tanhp(float x) {
  x = fminf(fmaxf(x, -15.f), 15.f);
  float e = __expf(-2.f * x);
  return (1.f - e) / (1.f + e);
}

// 16B load coherent at LLC — matches producers' sc1 write-through stores.
__device__ __forceinline__ u32x4 llc_load16(const unsigned short* p) {
  u32x4 r;
  asm volatile("global_load_dwordx4 %0, %1, off sc0 sc1" : "=v"(r) : "v"(p));
  return r;
}

__global__ void embed_kernel(const int* __restrict__ seqs, const float* __restrict__ E,
                             unsigned short* __restrict__ embb, float* __restrict__ out) {
  int b = blockIdx.x, t = blockIdx.y, d = threadIdx.x;
  int s = seqs[b * TT + t];
  float v = E[(size_t)s * NE + d];
  embb[((size_t)(b * TT + t)) * NE + d] = f2bf(v);
  if (t < TM) out[(((size_t)(0 * BB + b)) * TM + t) * NU + d] = v;       // fxs[0]
  if (t >= 1) out[(((size_t)(3 * BB + b)) * TM + (t - 1)) * NU + d] = v; // bxs[0]
}

__launch_bounds__(512, 1)
__global__ void lstm_kernel(const int* __restrict__ seqs,
                            const float* __restrict__ Wf, const float* __restrict__ Uf,
                            const float* __restrict__ bf,
                            const float* __restrict__ Wb, const float* __restrict__ Ub,
                            const float* __restrict__ bb,
                            const unsigned short* __restrict__ embb,
                            unsigned short* __restrict__ H0, unsigned short* __restrict__ H1,
                            int* __restrict__ ctr, float* __restrict__ out) {
  extern __shared__ char smem[];
  unsigned short* wlds = (unsigned short*)smem;     // 4 mats * 16384 ushort = 128KB
  float* zpart = (float*)(smem + 131072);           // [2][4][2][16][16] f32 = 16KB
  char* hlb0 = smem + 147456;                       // 8KB swizzled h0 tile
  char* hlb1 = smem + 155648;                       // 8KB swizzled h1 tile (tot 160KB)

  int tid = threadIdx.x;
  int blk = blockIdx.x;
  int cluster = blk & 7;
  int slice = blk >> 3;    // 0..15
  int dir = cluster >> 2;  // 0=fwd 1=bwd
  int rg = cluster & 3;    // rowgroup
  int ubase = slice << 4;  // unit base

  const float* W0 = dir ? Wb : Wf;
  const float* U0 = dir ? Ub : Uf;
  const float* W1 = W0 + NU * NG;
  const float* U1 = U0 + NU * NG;
  const float* b0p = dir ? bb : bf;
  const float* b1p = b0p + NG;

  // ---- pack weight slices into LDS (bf16 B-frag layout)
  // (gate g, col n, k) -> li = (g<<12)+(kb<<9)+(q<<7)+(n<<3)+j; kb=k>>5,q=(k>>3)&3,j=k&7
  {
    const float* srcs[4] = {W0, U0, W1, U1};
    int c = tid & 63;
    int gg = c >> 4, n = c & 15;
    int col = (gg << 8) + ubase + n;
    int koff = tid >> 6;  // 0..7
    for (int m = 0; m < 4; m++) {
      const float* S = srcs[m];
      unsigned short* WL = wlds + m * 16384;
      for (int k0 = 0; k0 < 256; k0 += 8) {
        int k = k0 + koff;
        float v = S[k * NG + col];
        int li = (gg << 12) + ((k >> 5) << 9) + (((k >> 3) & 3) << 7) + (n << 3) + (k & 7);
        WL[li] = f2bf(v);
      }
    }
  }

  // ---- roles ----
  int wave = tid >> 6;     // 0..7
  int g = wave & 3;        // gate
  int kh = wave >> 2;      // K-half
  int lane = tid & 63;
  int q = lane >> 4;       // 0..3
  int n15 = lane & 15;

  int tlay = tid >> 8;     // combine layer: 0 or 1
  int ct = tid & 255;
  int crow = ct >> 4, cn = ct & 15;
  int brow = rg * ROWG + crow;
  int cbase = cluster * (ROWG * NU);
  int* flags = ctr + cluster * 16;  // 16 per-slice flags, one 64B line

  // per-combine-thread bias + state (one layer each)
  float bi[4];
  {
    const float* bp = tlay ? b1p : b0p;
    #pragma unroll
    for (int gg = 0; gg < 4; gg++) bi[gg] = bp[(gg << 8) + ubase + cn];
  }
  float cst = 0.f, hv = 0.f;
  unsigned short* Hmine = (tlay ? H1 : H0);

  __syncthreads();

  const unsigned short* wb0 = wlds + (g << 12) + (kh << 11) + (q << 7) + (n15 << 3);
  const unsigned short* ub0 = wb0 + 16384;
  const unsigned short* wb1 = wb0 + 32768;
  const unsigned short* ub1 = wb0 + 49152;

  int fswz = (n15 & 7) << 4;
  int fbase = (n15 << 9) + (kh << 8) + (q << 4);  // byte off in 8KB h tile
  int zw = (g << 9) + (kh << 8) + n15;            // z-partial write base (+(row<<4))
  int zr = (tlay << 11) + (crow << 4) + cn;       // z read base (+(g<<9)+(kh<<8))

  for (int tau = 0; tau < NTICK; tau++) {
    bool doL0 = (tau < TM);

    // ---- mask prefetch (cached load, off critical path)
    int st = tlay ? (tau - 1) : tau;   // the step this thread combines this tick
    int mval = 0;
    if (st >= 0 && st < TM) {
      int traw = dir ? (TM - st) : st;
      mval = seqs[brow * TT + traw];
    }

    f32x4 acc0 = {0.f, 0.f, 0.f, 0.f};
    f32x4 acc1 = {0.f, 0.f, 0.f, 0.f};

    // ---- Phase A (pre-spin): x-part of layer0 = emb @ W0 (my K-half)
    if (doL0) {
      int tx = dir ? (TM - tau) : tau;
      const unsigned short* ep =
          embb + ((size_t)((rg * ROWG + n15) * TT + tx)) * NE + (kh << 7) + (q << 3);
      #pragma unroll
      for (int kb = 0; kb < 4; kb++) {
        short8 a = *reinterpret_cast<const short8*>(ep + (kb << 5));
        short8 b = *reinterpret_cast<const short8*>(wb0 + (kb << 9));
        acc0 = __builtin_amdgcn_mfma_f32_16x16x32_bf16(a, b, acc0, 0, 0, 0);
      }
    }

    if (tau > 0) {
      // ---- spin: wave0 polls the 16 per-slice flags (no RMW anywhere)
      if (wave == 0) {
        for (;;) {
          int v = 0x7fffffff;
          if (lane < 16)
            v = __hip_atomic_load(flags + lane, __ATOMIC_RELAXED,
                                  __HIP_MEMORY_SCOPE_AGENT);
          if (__all(v >= tau)) break;
        }
      }
      __syncthreads();

      // ---- cooperative 16B LLC loads of h tiles -> swizzled LDS
      int pb = (tau + 1) & 1;
      const unsigned short* src0 = H0 + pb * HSTRIDE + cbase;
      const unsigned short* src1 = H1 + pb * HSTRIDE + cbase;
      bool doH1 = (tau > 1);
      u32x4 t0 = llc_load16(src0 + tid * 8);
      u32x4 t1;
      if (doH1) t1 = llc_load16(src1 + tid * 8);
      asm volatile("s_waitcnt vmcnt(0)" ::: "memory");
      __builtin_amdgcn_sched_barrier(0);
      int w = (tid * 16) ^ ((((unsigned)tid >> 5) & 7) << 4);
      *(u32x4*)(hlb0 + w) = t0;
      if (doH1) *(u32x4*)(hlb1 + w) = t1;
      __syncthreads();

      // ---- h0[tau-1] @ U0 (L0) and @ W1 (L1); h1[tau-2] @ U1
      short8 ha[4];
      #pragma unroll
      for (int kb = 0; kb < 4; kb++)
        ha[kb] = *(const short8*)(hlb0 + ((fbase + (kb << 6)) ^ fswz));
      #pragma unroll
      for (int kb = 0; kb < 4; kb++) {
        if (doL0)
          acc0 = __builtin_amdgcn_mfma_f32_16x16x32_bf16(
              ha[kb], *reinterpret_cast<const short8*>(ub0 + (kb << 9)), acc0, 0, 0, 0);
        acc1 = __builtin_amdgcn_mfma_f32_16x16x32_bf16(
            ha[kb], *reinterpret_cast<const short8*>(wb1 + (kb << 9)), acc1, 0, 0, 0);
      }
      if (doH1) {
        short8 hb[4];
        #pragma unroll
        for (int kb = 0; kb < 4; kb++)
          hb[kb] = *(const short8*)(hlb1 + ((fbase + (kb << 6)) ^ fswz));
        #pragma unroll
        for (int kb = 0; kb < 4; kb++)
          acc1 = __builtin_amdgcn_mfma_f32_16x16x32_bf16(
              hb[kb], *reinterpret_cast<const short8*>(ub1 + (kb << 9)), acc1, 0, 0, 0);
      }
    }

    // ---- stage z partials (C layout: col=n15, row=q*4+j)
    if (doL0) {
      #pragma unroll
      for (int j = 0; j < 4; j++)
        zpart[zw + (((q << 2) + j) << 4)] = acc0[j];
    }
    if (tau > 0) {
      #pragma unroll
      for (int j = 0; j < 4; j++)
        zpart[2048 + zw + (((q << 2) + j) << 4)] = acc1[j];
    }
    __syncthreads();

    // ---- combine (parallel: tlay 0 -> L0, tlay 1 -> L1)
    bool act = tlay ? (tau > 0) : doL0;
    if (act) {
      float z[4];
      #pragma unroll
      for (int gg = 0; gg < 4; gg++)
        z[gg] = zpart[zr + (gg << 9)] + zpart[zr + (gg << 9) + 256] + bi[gg];
      float cnw = sigm(z[1]) * cst + sigm(z[0]) * tanhp(z[2]);
      float hnw = sigm(z[3]) * tanhp(cnw);
      if (mval) { cst = cnw; hv = hnw; }
      unsigned int hb16 = f2bf(hv);
      unsigned int othr = (unsigned int)__shfl_xor((int)hb16, 1, 64);
      if (!(cn & 1)) {
        unsigned int packed = (hb16 & 0xFFFFu) | (othr << 16);
        __hip_atomic_store(
            (unsigned int*)(Hmine + (tau & 1) * HSTRIDE + cbase + (crow << 8) + ubase + cn),
            packed, __ATOMIC_RELAXED, __HIP_MEMORY_SCOPE_AGENT);
      }
    }

    // ---- publish: barrier drains vmcnt (H stores ack'd), then flag store
    __syncthreads();
    if (tau < TM && tid == 0)
      __hip_atomic_store(flags + slice, tau + 1, __ATOMIC_RELAXED,
                         __HIP_MEMORY_SCOPE_AGENT);

    // ---- out[] fp32 stores (off critical path)
    if (act) {
      int tout = dir ? (TM - 1 - st) : st;
      out[(((size_t)((1 + tlay + dir * 3) * BB + brow)) * TM + tout) * NU + ubase + cn] = hv;
    }
  }
}

extern "C" void kernel_launch(void* const* d_in, const int* in_sizes, int n_in,
                              void* d_out, int out_size, void* d_ws, size_t ws_size,
                              hipStream_t stream) {
  const int* seqs = (const int*)d_in[0];
  const float* E = (const float*)d_in[1];
  const float* Wf = (const float*)d_in[2];
  const float* Uf = (const float*)d_in[3];
  const float* bfp = (const float*)d_in[4];
  const float* Wb = (const float*)d_in[5];
  const float* Ub = (const float*)d_in[6];
  const float* bbp = (const float*)d_in[7];
  float* out = (float*)d_out;

  char* ws = (char*)d_ws;
  int* ctr = (int*)ws;                                           // flags
  unsigned short* embb = (unsigned short*)(ws + 65536);          // 8 MB bf16 emb
  unsigned short* H0 = (unsigned short*)(ws + 65536 + 8388608);  // 2x64KB
  unsigned short* H1 = H0 + 2 * HSTRIDE;

  hipMemsetAsync(ctr, 0, NCLUST * 16 * sizeof(int), stream);

  hipLaunchKernelGGL(embed_kernel, dim3(BB, TT), dim3(256), 0, stream,
                     seqs, E, embb, out);

  int smem = 163840;  // 128K weights + 16K zpart + 2x8K h tiles (full LDS)
  hipFuncSetAttribute(reinterpret_cast<const void*>(lstm_kernel),
                      hipFuncAttributeMaxDynamicSharedMemorySize, smem);
  hipLaunchKernelGGL(lstm_kernel, dim3(128), dim3(512), smem, stream,
                     seqs, Wf, Uf, bfp, Wb, Ub, bbp, embb, H0, H1, ctr, out);
}